// Round 5
// baseline (392.132 us; speedup 1.0000x reference)
//
#include <hip/hip_runtime.h>
#include <hip/hip_bf16.h>

#define B_  4096
#define F_  26
#define E_  64
#define D_  1664
#define N1_ 1024
#define N2_ 512
#define N3_ 256

typedef __attribute__((ext_vector_type(8)))  __bf16         bf16x8;
typedef __attribute__((ext_vector_type(8)))  unsigned short u16x8;
typedef __attribute__((ext_vector_type(16))) float          f32x16;

__device__ __forceinline__ unsigned short f2b(float x) {
    __hip_bfloat16 h = __float2bfloat16(x);
    return __builtin_bit_cast(unsigned short, h);
}
__device__ __forceinline__ float b2f(unsigned short u) {
    return __uint_as_float(((unsigned)u) << 16);
}

// ---------------------------------------------------------------------------
// Fragment-packed operand layout for mfma_f32_32x32x16_bf16:
//   A_packed[mtile32][kslab16][lane][8]  lane = (row&31) + 32*((k>>3)&1)
//   B_packed[ntile32][kslab16][lane][8]  lane = (col&31) + 32*((k>>3)&1)
// One wave instruction loads one fragment = contiguous 1 KB (dwordx4/lane).
// ---------------------------------------------------------------------------

// ---------------- fused gather + cross + head-partial + A1-pack ------------
// One block per batch row. Thread t<208 owns k = t*8..t*8+7 (one 16B frag store).
__global__ __launch_bounds__(256) void gather_cross_kernel(
        const int* __restrict__ ids, const float* __restrict__ emb,
        const float* __restrict__ cw, const float* __restrict__ cb,
        const float* __restrict__ out_w,
        u16x8* __restrict__ x0p, float* __restrict__ partial)
{
    __shared__ int   sid[F_];
    __shared__ float red[4];
    const int b = blockIdx.x;
    const int t = threadIdx.x;
    const int lane = t & 63, w = t >> 6;
    const bool act = (t < 208);          // 208*8 = 1664

    if (t < F_) sid[t] = ids[b * F_ + t];
    __syncthreads();

    const float4* emb4 = (const float4*)emb;
    const float4* cw4  = (const float4*)cw;
    const float4* cb4  = (const float4*)cb;
    const float4* ow4  = (const float4*)out_w;

    float4 x00 = make_float4(0,0,0,0), x01 = x00, xv0 = x00, xv1 = x00;
    if (act) {
        const int f  = t >> 3;           // field of k=t*8
        const int c0 = 2 * t;
        x00 = emb4[(size_t)sid[f] * 16 + (c0 & 15)];
        x01 = emb4[(size_t)sid[f] * 16 + ((c0 + 1) & 15)];
        u16x8 o;
        o[0]=f2b(x00.x); o[1]=f2b(x00.y); o[2]=f2b(x00.z); o[3]=f2b(x00.w);
        o[4]=f2b(x01.x); o[5]=f2b(x01.y); o[6]=f2b(x01.z); o[7]=f2b(x01.w);
        const int mt = b >> 5, ks = t >> 1, ls = (b & 31) + 32 * (t & 1);
        x0p[((size_t)mt * 104 + ks) * 64 + ls] = o;
        xv0 = x00; xv1 = x01;
    }
    for (int i = 0; i < 3; i++) {
        float s = 0.f;
        if (act) {
            const float4 wa = cw4[i * 416 + 2 * t];
            const float4 wb = cw4[i * 416 + 2 * t + 1];
            s = xv0.x*wa.x + xv0.y*wa.y + xv0.z*wa.z + xv0.w*wa.w
              + xv1.x*wb.x + xv1.y*wb.y + xv1.z*wb.z + xv1.w*wb.w;
        }
        #pragma unroll
        for (int off = 32; off > 0; off >>= 1) s += __shfl_down(s, off, 64);
        __syncthreads();
        if (lane == 0) red[w] = s;
        __syncthreads();
        const float st = red[0] + red[1] + red[2] + red[3];
        if (act) {
            const float4 ba = cb4[i * 416 + 2 * t];
            const float4 bb = cb4[i * 416 + 2 * t + 1];
            xv0.x = x00.x*st + ba.x + xv0.x;  xv0.y = x00.y*st + ba.y + xv0.y;
            xv0.z = x00.z*st + ba.z + xv0.z;  xv0.w = x00.w*st + ba.w + xv0.w;
            xv1.x = x01.x*st + bb.x + xv1.x;  xv1.y = x01.y*st + bb.y + xv1.y;
            xv1.z = x01.z*st + bb.z + xv1.z;  xv1.w = x01.w*st + bb.w + xv1.w;
        }
    }
    float s = 0.f;
    if (act) {
        const float4 wa = ow4[2 * t];
        const float4 wb = ow4[2 * t + 1];
        s = xv0.x*wa.x + xv0.y*wa.y + xv0.z*wa.z + xv0.w*wa.w
          + xv1.x*wb.x + xv1.y*wb.y + xv1.z*wb.z + xv1.w*wb.w;
    }
    #pragma unroll
    for (int off = 32; off > 0; off >>= 1) s += __shfl_down(s, off, 64);
    __syncthreads();
    if (lane == 0) red[w] = s;
    __syncthreads();
    if (t == 0) partial[b] = red[0] + red[1] + red[2] + red[3];
}

// ---------------- weights -> B-fragment pack (all 3 layers) ----------------
// Each block: one (ntile32 x 128k) slab. w1: 32x13=416, w2: 16x8=128, w3: 8x4=32.
__global__ __launch_bounds__(256) void pack_weights_kernel(
        const float* __restrict__ w1, const float* __restrict__ w2,
        const float* __restrict__ w3,
        u16x8* __restrict__ p1, u16x8* __restrict__ p2, u16x8* __restrict__ p3)
{
    __shared__ float tile[128][33];
    const int bid = blockIdx.x;
    const float* in; u16x8* out; int N, ntiles, KS;
    int tl;
    if (bid < 416)      { in = w1; out = p1; N = N1_; ntiles = 32; KS = 104; tl = bid; }
    else if (bid < 544) { in = w2; out = p2; N = N2_; ntiles = 16; KS = 64;  tl = bid - 416; }
    else                { in = w3; out = p3; N = N3_; ntiles = 8;  KS = 32;  tl = bid - 544; }
    const int nt = tl % ntiles;
    const int kg = tl / ntiles;
    const int t  = threadIdx.x;

    #pragma unroll
    for (int p = 0; p < 16; p++) {
        const int row = p * 8 + (t >> 5);
        tile[row][t & 31] = in[(size_t)(kg * 128 + row) * N + nt * 32 + (t & 31)];
    }
    __syncthreads();
    #pragma unroll
    for (int q = 0; q < 2; q++) {
        const int idx = q * 256 + t;
        const int ksl = idx >> 6, l = idx & 63;
        const int kr  = ksl * 16 + (l >> 5) * 8;
        u16x8 o;
        #pragma unroll
        for (int e = 0; e < 8; e++) o[e] = f2b(tile[kr + e][l & 31]);
        out[((size_t)nt * KS + kg * 8 + ksl) * 64 + l] = o;
    }
}

// ---------------- LDS-free register-streaming MFMA GEMM --------------------
// C = relu(A @ B^T + bias); A,B fragment-packed bf16; fp32 acc (32x32x16 MFMA).
// Wave-tile = (TI*32) x (TJ*32); block = 2x2 waves. No barriers in K-loop.
// PACK_OUT: epilogue re-packs output into next layer's A-fragment layout via
// wave-private LDS transpose. Else row-major bf16.
template<int TI, int TJ, int KS, bool PACK_OUT>
__global__ __launch_bounds__(256) void stream_gemm(
        const u16x8* __restrict__ Ap, const u16x8* __restrict__ Bp,
        const float* __restrict__ bias, void* __restrict__ Cout,
        int N, int KSo)
{
    const int t = threadIdx.x, lane = t & 63, w = t >> 6;
    const int wy = w >> 1, wx = w & 1;

    // XCD-aware swizzle (gridDim.y divisible by 8)
    const int i   = blockIdx.y * gridDim.x + blockIdx.x;
    const int xcd = i & 7, s = i >> 3;
    const int ypg = gridDim.y >> 3;
    const int by  = xcd * ypg + s / gridDim.x;
    const int bx  = s % gridDim.x;
    const int mt0 = (by * 2 + wy) * TI;      // 32-row units
    const int nt0 = (bx * 2 + wx) * TJ;      // 32-col units

    f32x16 acc[TI][TJ] = {};

    #pragma unroll 4
    for (int ks = 0; ks < KS; ks++) {
        bf16x8 af[TI], bf[TJ];
        #pragma unroll
        for (int a = 0; a < TI; a++)
            af[a] = __builtin_bit_cast(bf16x8,
                Ap[((size_t)(mt0 + a) * KS + ks) * 64 + lane]);
        #pragma unroll
        for (int b = 0; b < TJ; b++)
            bf[b] = __builtin_bit_cast(bf16x8,
                Bp[((size_t)(nt0 + b) * KS + ks) * 64 + lane]);
        #pragma unroll
        for (int a = 0; a < TI; a++)
            #pragma unroll
            for (int b = 0; b < TJ; b++)
                acc[a][b] = __builtin_amdgcn_mfma_f32_32x32x16_bf16(
                    af[a], bf[b], acc[a][b], 0, 0, 0);
    }

    // C/D layout (32x32): col=lane&31, row=(reg&3)+8*(reg>>2)+4*(lane>>5)
    if (PACK_OUT) {
        constexpr int PITCH = TJ * 32 + 8;           // shorts; 16B-aligned rows
        __shared__ __align__(16) unsigned short lt[4 * TI * 32 * PITCH];
        unsigned short* L = lt + w * TI * 32 * PITCH;
        #pragma unroll
        for (int a = 0; a < TI; a++)
            #pragma unroll
            for (int b = 0; b < TJ; b++) {
                const float bv = bias[(nt0 + b) * 32 + (lane & 31)];
                #pragma unroll
                for (int r = 0; r < 16; r++) {
                    const int row_l = a * 32 + (r & 3) + 8 * (r >> 2) + 4 * (lane >> 5);
                    const int col_l = b * 32 + (lane & 31);
                    L[row_l * PITCH + col_l] = f2b(fmaxf(acc[a][b][r] + bv, 0.f));
                }
            }
        u16x8* Co = (u16x8*)Cout;
        #pragma unroll
        for (int a = 0; a < TI; a++)
            #pragma unroll
            for (int ksl = 0; ksl < TJ * 2; ksl++) {
                const u16x8 v = *(const u16x8*)
                    &L[(a * 32 + (lane & 31)) * PITCH + ksl * 16 + (lane >> 5) * 8];
                Co[((size_t)(mt0 + a) * KSo + (nt0 * 2 + ksl)) * 64 + lane] = v;
            }
    } else {
        unsigned short* Co = (unsigned short*)Cout;
        #pragma unroll
        for (int a = 0; a < TI; a++)
            #pragma unroll
            for (int b = 0; b < TJ; b++) {
                const int colg = (nt0 + b) * 32 + (lane & 31);
                const float bv = bias[colg];
                #pragma unroll
                for (int r = 0; r < 16; r++) {
                    const int rowg = (mt0 + a) * 32 + (r & 3) + 8 * (r >> 2) + 4 * (lane >> 5);
                    Co[(size_t)rowg * N + colg] = f2b(fmaxf(acc[a][b][r] + bv, 0.f));
                }
            }
    }
}

// ---------------------------------------------------------------- head
__global__ __launch_bounds__(256) void head_kernel(
        const float* __restrict__ partial, const unsigned short* __restrict__ h3,
        const float* __restrict__ out_w, const float* __restrict__ out_b,
        float* __restrict__ out)
{
    const int gw   = (blockIdx.x * 256 + threadIdx.x) >> 6;  // one wave per row
    const int lane = threadIdx.x & 63;
    if (gw >= B_) return;
    float s = 0.f;
    #pragma unroll
    for (int q = 0; q < 4; q++) {
        const int j = lane + q * 64;
        s += b2f(h3[(size_t)gw * N3_ + j]) * out_w[D_ + j];
    }
    #pragma unroll
    for (int off = 32; off > 0; off >>= 1) s += __shfl_down(s, off, 64);
    if (lane == 0) {
        const float logit = partial[gw] + s + out_b[0];
        out[gw] = 1.f / (1.f + expf(-logit));
    }
}

extern "C" void kernel_launch(void* const* d_in, const int* in_sizes, int n_in,
                              void* d_out, int out_size, void* d_ws, size_t ws_size,
                              hipStream_t stream)
{
    (void)in_sizes; (void)n_in; (void)out_size; (void)ws_size;
    const int*   ids     = (const int*)  d_in[0];
    const float* emb     = (const float*)d_in[1];
    const float* cross_w = (const float*)d_in[2];
    const float* cross_b = (const float*)d_in[3];
    const float* w1      = (const float*)d_in[4];
    const float* b1      = (const float*)d_in[5];
    const float* w2      = (const float*)d_in[6];
    const float* b2      = (const float*)d_in[7];
    const float* w3      = (const float*)d_in[8];
    const float* b3      = (const float*)d_in[9];
    const float* out_w   = (const float*)d_in[10];
    const float* out_b   = (const float*)d_in[11];
    float* out = (float*)d_out;

    char* p = (char*)d_ws;
    auto alloc = [&](size_t bytes) {
        char* r = p; p += (bytes + 255) & ~(size_t)255; return r;
    };
    u16x8* x0p = (u16x8*)alloc((size_t)B_ * D_ * 2);          // [128][104][64][8]
    u16x8* w1p = (u16x8*)alloc((size_t)D_ * N1_ * 2);         // [32][104][64][8]
    u16x8* w2p = (u16x8*)alloc((size_t)N1_ * N2_ * 2);        // [16][64][64][8]
    u16x8* w3p = (u16x8*)alloc((size_t)N2_ * N3_ * 2);        // [8][32][64][8]
    u16x8* h1p = (u16x8*)alloc((size_t)B_ * N1_ * 2);         // [128][64][64][8]
    u16x8* h2p = (u16x8*)alloc((size_t)B_ * N2_ * 2);         // [128][32][64][8]
    unsigned short* h3 = (unsigned short*)alloc((size_t)B_ * N3_ * 2);  // row-major
    float* partial     = (float*)alloc((size_t)B_ * 4);

    gather_cross_kernel<<<B_, 256, 0, stream>>>(
        ids, emb, cross_w, cross_b, out_w, x0p, partial);
    pack_weights_kernel<<<576, 256, 0, stream>>>(w1, w2, w3, w1p, w2p, w3p);

    // LDS-free streaming GEMMs: 1024 independent waves each
    stream_gemm<2, 2, 104, true><<<dim3(8, 32), 256, 0, stream>>>(
        x0p, w1p, b1, h1p, N1_, N1_ / 16);
    stream_gemm<2, 1, 64, true><<<dim3(8, 32), 256, 0, stream>>>(
        h1p, w2p, b2, h2p, N2_, N2_ / 16);
    stream_gemm<1, 1, 32, false><<<dim3(4, 64), 256, 0, stream>>>(
        h2p, w3p, b3, h3, N3_, 0);

    head_kernel<<<B_ / 4, 256, 0, stream>>>(partial, h3, out_w, out_b, out);
}